// Round 1
// baseline (183.629 us; speedup 1.0000x reference)
//
#include <hip/hip_runtime.h>

#define B_    4
#define N_    2048
#define HID_  768
#define NH_   12
#define E_    131072
#define M_    8192   // B_*N_

typedef unsigned short u16;
typedef unsigned int   u32;
typedef short bf16x8 __attribute__((ext_vector_type(8)));
typedef float f32x4  __attribute__((ext_vector_type(4)));

__device__ __forceinline__ u16 f2bf(float x) {
  u32 u = __float_as_uint(x);
  u += 0x7fffu + ((u >> 16) & 1u);   // RNE
  return (u16)(u >> 16);
}
__device__ __forceinline__ float bflo(u32 u) { return __uint_as_float(u << 16); }
__device__ __forceinline__ float bfhi(u32 u) { return __uint_as_float(u & 0xffff0000u); }

__device__ __forceinline__ void load_lds16(const u16* g, u16* l) {
  // async global->LDS, 16B per lane; LDS dest = wave-uniform base + lane*16
  __builtin_amdgcn_global_load_lds((__attribute__((address_space(1))) void*)(g),
                                   (__attribute__((address_space(3))) void*)(l),
                                   16, 0, 0);
}

// ---------------- Kernel 0: f32 -> bf16 convert (X, Wq, Wk, Wv) ----------------
__global__ __launch_bounds__(256) void k_convert(
    const float4* __restrict__ X, const float4* __restrict__ Wq,
    const float4* __restrict__ Wk, const float4* __restrict__ Wv,
    ushort4* __restrict__ Xbf, ushort4* __restrict__ Wbf) {
  const int NX4 = (M_ * HID_) / 4;     // 1572864
  const int NW4 = (HID_ * HID_) / 4;   // 147456
  int tid = blockIdx.x * 256 + threadIdx.x;
  const float4* src; ushort4* dst; int off;
  if (tid < NX4) { src = X; dst = Xbf; off = tid; }
  else {
    int t2 = tid - NX4;
    int wi = t2 / NW4;
    off = t2 - wi * NW4;
    src = (wi == 0) ? Wq : (wi == 1) ? Wk : Wv;
    dst = Wbf + (size_t)wi * NW4;
  }
  float4 v = src[off];
  ushort4 o;
  o.x = f2bf(v.x); o.y = f2bf(v.y); o.z = f2bf(v.z); o.w = f2bf(v.w);
  dst[off] = o;
}

// ---------------- Kernel 1: fused QKV GEMM, bf16 MFMA ----------------
// C[m,n] = sum_k X[m,k]*W[n,k] + bias[n]  (NT gemm), tile 128x128, BK=64.
// LDS layout: row-major [128][64] bf16, 16B chunks XOR-swizzled: chunk g of row m
// stored at slot g^(m&7)  ->  staging stays lane*16-contiguous, ds_read_b128
// spreads over all 8 bank-groups (conflict-floor).
__global__ __launch_bounds__(256, 2) void k_gemm(
    const u16* __restrict__ Xbf, const u16* __restrict__ Wbf,
    const float* __restrict__ bq, const float* __restrict__ bk, const float* __restrict__ bv,
    u16* __restrict__ Qb, u16* __restrict__ Kb, u16* __restrict__ Vb) {
  __shared__ u16 As[128 * 64];
  __shared__ u16 Bs[128 * 64];
  const int tid = threadIdx.x;
  const int w = tid >> 6, lane = tid & 63;
  const int m0 = blockIdx.x * 128;
  const int ny = blockIdx.y;            // 0..17
  const int widx = ny / 6;              // 0:Q 1:K 2:V
  const int nl0 = (ny - widx * 6) * 128;
  const u16* Wp = Wbf + (size_t)widx * (HID_ * HID_);
  u16* Op = (widx == 0) ? Qb : (widx == 1) ? Kb : Vb;
  const float* bias = (widx == 0) ? bq : (widx == 1) ? bk : bv;

  f32x4 acc[4][4] = {};
  const int wm = w >> 1, wn = w & 1;
  const int lm = lane & 15, lg = lane >> 4;

  for (int kt = 0; kt < HID_ / 64; ++kt) {
    const int k0 = kt * 64;
    __syncthreads();
#pragma unroll
    for (int ii = 0; ii < 4; ++ii) {
      const int sb = (ii * 4 + w) * 64;
      const int s = sb + lane;
      const int m = s >> 3;
      const int g = (s & 7) ^ (m & 7);
      load_lds16(Xbf + (size_t)(m0 + m) * HID_ + k0 + g * 8, &As[sb * 8]);
      load_lds16(Wp + (size_t)(nl0 + m) * HID_ + k0 + g * 8, &Bs[sb * 8]);
    }
    __syncthreads();
#pragma unroll
    for (int kk = 0; kk < 2; ++kk) {
      bf16x8 af[4], bfr[4];
#pragma unroll
      for (int mt = 0; mt < 4; ++mt) {
        const int m = wm * 64 + mt * 16 + lm;
        const int g = (kk * 4 + lg) ^ (m & 7);
        af[mt] = *(const bf16x8*)&As[m * 64 + g * 8];
      }
#pragma unroll
      for (int nt = 0; nt < 4; ++nt) {
        const int n = wn * 64 + nt * 16 + lm;
        const int g = (kk * 4 + lg) ^ (n & 7);
        bfr[nt] = *(const bf16x8*)&Bs[n * 64 + g * 8];
      }
#pragma unroll
      for (int mt = 0; mt < 4; ++mt)
#pragma unroll
        for (int nt = 0; nt < 4; ++nt)
          acc[mt][nt] = __builtin_amdgcn_mfma_f32_16x16x32_bf16(af[mt], bfr[nt], acc[mt][nt], 0, 0, 0);
    }
  }
  // epilogue: D layout col=lane&15, row=(lane>>4)*4+reg  [m89]
#pragma unroll
  for (int nt = 0; nt < 4; ++nt) {
    const int c = nl0 + wn * 64 + nt * 16 + lm;
    const float bb = bias[c];
#pragma unroll
    for (int mt = 0; mt < 4; ++mt) {
      const int rbase = m0 + wm * 64 + mt * 16 + lg * 4;
#pragma unroll
      for (int r = 0; r < 4; ++r)
        Op[(size_t)(rbase + r) * HID_ + c] = f2bf(acc[mt][nt][r] + bb);
    }
  }
}

// ---------------- Kernel 2: edge attention ----------------
// wave per group (b,i): lane = (edge j = lane>>2, d-quarter qd = lane&3)
__global__ __launch_bounds__(256) void k_attn(
    const u16* __restrict__ Qb, const u16* __restrict__ Kb, const u16* __restrict__ Vb,
    const float* __restrict__ rel, const int* __restrict__ eidx,
    float* __restrict__ out) {
  __shared__ float p_s[4 * 16 * NH_];
  const int w = threadIdx.x >> 6, lane = threadIdx.x & 63;
  // XCD swizzle: give each XCD a contiguous range of groups for K/V L2 locality
  const int gb = ((int)blockIdx.x & 7) * 256 + ((int)blockIdx.x >> 3);
  const int g = gb * 4 + w;
  const int e0 = g * 16;
  const int* tb = eidx;
  const int* ti = eidx + E_;
  const int* tt = eidx + 2 * E_;
  const int* tr = eidx + 3 * E_;
  const int b = tb[e0], i = ti[e0];
  const int j = lane >> 2, qd = lane & 3;
  const int t = tt[e0 + j], r = tr[e0 + j];
  const u16* Krow = Kb + (size_t)(b * N_ + t) * HID_;
  const u16* Qrow = Qb + (size_t)(b * N_ + i) * HID_;
  const float* Rrow = rel + (size_t)r * HID_;

  for (int h = 0; h < NH_; ++h) {
    const int base = h * 64 + qd * 16;
    uint4 ku0 = *(const uint4*)(Krow + base);
    uint4 ku1 = *(const uint4*)(Krow + base + 8);
    uint4 qu0 = *(const uint4*)(Qrow + base);
    uint4 qu1 = *(const uint4*)(Qrow + base + 8);
    float4 rf0 = *(const float4*)(Rrow + base);
    float4 rf1 = *(const float4*)(Rrow + base + 4);
    float4 rf2 = *(const float4*)(Rrow + base + 8);
    float4 rf3 = *(const float4*)(Rrow + base + 12);
    float s = 0.f;
    s += bflo(qu0.x) * (bflo(ku0.x) - rf0.x);
    s += bfhi(qu0.x) * (bfhi(ku0.x) - rf0.y);
    s += bflo(qu0.y) * (bflo(ku0.y) - rf0.z);
    s += bfhi(qu0.y) * (bfhi(ku0.y) - rf0.w);
    s += bflo(qu0.z) * (bflo(ku0.z) - rf1.x);
    s += bfhi(qu0.z) * (bfhi(ku0.z) - rf1.y);
    s += bflo(qu0.w) * (bflo(ku0.w) - rf1.z);
    s += bfhi(qu0.w) * (bfhi(ku0.w) - rf1.w);
    s += bflo(qu1.x) * (bflo(ku1.x) - rf2.x);
    s += bfhi(qu1.x) * (bfhi(ku1.x) - rf2.y);
    s += bflo(qu1.y) * (bflo(ku1.y) - rf2.z);
    s += bfhi(qu1.y) * (bfhi(ku1.y) - rf2.w);
    s += bflo(qu1.z) * (bflo(ku1.z) - rf3.x);
    s += bfhi(qu1.z) * (bfhi(ku1.z) - rf3.y);
    s += bflo(qu1.w) * (bflo(ku1.w) - rf3.z);
    s += bfhi(qu1.w) * (bfhi(ku1.w) - rf3.w);
    // reduce over the 4 d-quarters (xor 1,2), then softmax over 16 edges (xor 4..32)
    s += __shfl_xor(s, 1);
    s += __shfl_xor(s, 2);
    const float logit = s * 0.125f;   // /sqrt(64)
    float mx = logit;
    mx = fmaxf(mx, __shfl_xor(mx, 4));
    mx = fmaxf(mx, __shfl_xor(mx, 8));
    mx = fmaxf(mx, __shfl_xor(mx, 16));
    mx = fmaxf(mx, __shfl_xor(mx, 32));
    const float ex = __expf(logit - mx);
    float den = ex;
    den += __shfl_xor(den, 4);
    den += __shfl_xor(den, 8);
    den += __shfl_xor(den, 16);
    den += __shfl_xor(den, 32);
    if (qd == 0) p_s[(w * 16 + j) * NH_ + h] = ex / den;
  }
  __syncthreads();

  // aggregation: lane handles bf16x8 chunk c8=lane (h=lane>>3) and, for lane<32,
  // chunk c8=64+lane (h=8+(lane>>3)); fully coalesced V row reads.
  float a0[8] = {0.f, 0.f, 0.f, 0.f, 0.f, 0.f, 0.f, 0.f};
  float a1[8] = {0.f, 0.f, 0.f, 0.f, 0.f, 0.f, 0.f, 0.f};
  for (int j2 = 0; j2 < 16; ++j2) {
    const int t2 = tt[e0 + j2];
    const u16* Vrow = Vb + (size_t)(b * N_ + t2) * HID_;
    uint4 v0 = *(const uint4*)(Vrow + lane * 8);
    const float p0 = p_s[(w * 16 + j2) * NH_ + (lane >> 3)];
    a0[0] += p0 * bflo(v0.x); a0[1] += p0 * bfhi(v0.x);
    a0[2] += p0 * bflo(v0.y); a0[3] += p0 * bfhi(v0.y);
    a0[4] += p0 * bflo(v0.z); a0[5] += p0 * bfhi(v0.z);
    a0[6] += p0 * bflo(v0.w); a0[7] += p0 * bfhi(v0.w);
    if (lane < 32) {
      uint4 v1 = *(const uint4*)(Vrow + 512 + lane * 8);
      const float p1 = p_s[(w * 16 + j2) * NH_ + 8 + (lane >> 3)];
      a1[0] += p1 * bflo(v1.x); a1[1] += p1 * bfhi(v1.x);
      a1[2] += p1 * bflo(v1.y); a1[3] += p1 * bfhi(v1.y);
      a1[4] += p1 * bflo(v1.z); a1[5] += p1 * bfhi(v1.z);
      a1[6] += p1 * bflo(v1.w); a1[7] += p1 * bfhi(v1.w);
    }
  }
  float* orow = out + (size_t)(b * N_ + i) * HID_;
  *(float4*)(orow + lane * 8)     = make_float4(a0[0], a0[1], a0[2], a0[3]);
  *(float4*)(orow + lane * 8 + 4) = make_float4(a0[4], a0[5], a0[6], a0[7]);
  if (lane < 32) {
    *(float4*)(orow + 512 + lane * 8)     = make_float4(a1[0], a1[1], a1[2], a1[3]);
    *(float4*)(orow + 512 + lane * 8 + 4) = make_float4(a1[4], a1[5], a1[6], a1[7]);
  }
}

extern "C" void kernel_launch(void* const* d_in, const int* in_sizes, int n_in,
                              void* d_out, int out_size, void* d_ws, size_t ws_size,
                              hipStream_t stream) {
  const float* X   = (const float*)d_in[0];
  const int*   eidx= (const int*)d_in[1];
  const float* Wq  = (const float*)d_in[2];
  const float* bq  = (const float*)d_in[3];
  const float* Wk  = (const float*)d_in[4];
  const float* bk  = (const float*)d_in[5];
  const float* Wv  = (const float*)d_in[6];
  const float* bv  = (const float*)d_in[7];
  const float* rel = (const float*)d_in[8];
  float* out = (float*)d_out;

  // ws layout (bytes): Xbf 12,582,912 | Wbf 3,538,944 | Qb/Kb/Vb 12,582,912 each = 53.9 MB
  char* ws = (char*)d_ws;
  u16* Xbf = (u16*)(ws);
  u16* Wbf = (u16*)(ws + 12582912);
  u16* Qb  = (u16*)(ws + 16121856);
  u16* Kb  = (u16*)(ws + 28704768);
  u16* Vb  = (u16*)(ws + 41287680);

  k_convert<<<7872, 256, 0, stream>>>((const float4*)X, (const float4*)Wq,
                                      (const float4*)Wk, (const float4*)Wv,
                                      (ushort4*)Xbf, (ushort4*)Wbf);
  k_gemm<<<dim3(64, 18), 256, 0, stream>>>(Xbf, Wbf, bq, bk, bv, Qb, Kb, Vb);
  k_attn<<<2048, 256, 0, stream>>>(Qb, Kb, Vb, rel, eidx, out);
}